// Round 1
// baseline (15016.583 us; speedup 1.0000x reference)
//
#include <hip/hip_runtime.h>

// ---- problem constants ----
constexpr int   NN  = 50000;            // nodes
constexpr int   NE  = 600000;           // edges
constexpr long  EA  = NE + NN;          // augmented edges (self loops appended)
constexpr int   ND  = 128;              // node dim
constexpr int   ED  = 64;               // edge dim
constexpr int   HD  = 128;              // hidden dim

// ---- float atomic-max via monotonic uint encoding ----
__device__ inline unsigned fenc(float x) {
    unsigned u = __float_as_uint(x);
    return (u & 0x80000000u) ? ~u : (u | 0x80000000u);
}
__device__ inline float fdec(unsigned k) {
    return (k & 0x80000000u) ? __uint_as_float(k ^ 0x80000000u) : __uint_as_float(~k);
}

// =====================================================================
// K1: ee = relu(edge_attr @ ep_w + ep_b); scatter sums for x_out/x_in,
//     loop_attr sum, degree counts.  lane = edge, 64 edges/block.
// =====================================================================
__global__ __launch_bounds__(256) void k_edge_proj(
    const float* __restrict__ eattr, const int* __restrict__ src, const int* __restrict__ dst,
    const float* __restrict__ ep_w, const float* __restrict__ ep_b,
    float* __restrict__ xo, float* __restrict__ xi, float* __restrict__ loopa,
    float* __restrict__ cs, float* __restrict__ cd)
{
    __shared__ float ea_lds[64][65];                   // +1 pad -> conflict-free column reads
    const int lane = threadIdx.x & 63;
    const int wid  = __builtin_amdgcn_readfirstlane(threadIdx.x >> 6);
    const long e0  = (long)blockIdx.x * 64;

    for (int r = wid; r < 64; r += 4) {
        long e = e0 + r;
        ea_lds[r][lane] = (e < NE) ? eattr[e * ED + lane] : 0.f;
    }
    __syncthreads();

    const long e  = e0 + lane;
    const bool val = (e < NE);
    const int s = val ? src[e] : 0;
    const int d = val ? dst[e] : 0;
    const int c0 = wid * 32;                            // this wave's 32 output cols

    float acc[32];
    #pragma unroll
    for (int j = 0; j < 32; ++j) acc[j] = ep_b[c0 + j];           // uniform -> s_load
    for (int k = 0; k < 64; ++k) {
        float a = ea_lds[lane][k];
        const float* wrow = ep_w + k * ND + c0;                    // uniform -> s_load
        #pragma unroll
        for (int j = 0; j < 32; ++j) acc[j] = fmaf(a, wrow[j], acc[j]);
    }
    if (val) {
        #pragma unroll
        for (int j = 0; j < 32; ++j) {
            float v = fmaxf(acc[j], 0.f);
            atomicAdd(&xo[(long)s * ND + c0 + j], v);
            atomicAdd(&xi[(long)d * ND + c0 + j], v);
        }
        for (int k = wid * 16; k < wid * 16 + 16; ++k)             // loop_attr sum (split over waves)
            atomicAdd(&loopa[(long)d * ED + k], ea_lds[lane][k]);
        if (wid == 0) { atomicAdd(&cs[s], 1.f); atomicAdd(&cd[d], 1.f); }
    }
}

// =====================================================================
// K2: finalize x_input = [x_out_mean | x_in_mean]; loop_attr /= cnt_dst
// =====================================================================
__global__ void k_finalize(const float* __restrict__ xo, const float* __restrict__ xi,
                           const float* __restrict__ cs, const float* __restrict__ cd,
                           float* __restrict__ x_input, float* __restrict__ loopa)
{
    long i = (long)blockIdx.x * blockDim.x + threadIdx.x;          // over N*128
    if (i >= (long)NN * 128) return;
    int n = (int)(i >> 7), c = (int)(i & 127);
    float co = fmaxf(cs[n], 1.f), ci = fmaxf(cd[n], 1.f);
    x_input[(long)n * 256 + c]       = xo[i] / co;
    x_input[(long)n * 256 + 128 + c] = xi[i] / ci;
    if (c < 64) loopa[(long)n * 64 + c] /= ci;
}

// =====================================================================
// K3: generic dense GEMM  C[M,NC] = A[M,KD] @ W[KD,NC]
//     lane = row, 64 rows/block, W via scalar loads.
// =====================================================================
template<int KD, int NC>
__global__ __launch_bounds__(256) void k_gemm(const float* __restrict__ A,
                                              const float* __restrict__ W,
                                              float* __restrict__ C, int M)
{
    constexpr int CPW = NC / 4;                        // cols per wave
    __shared__ float a_lds[64][65];
    const int lane = threadIdx.x & 63;
    const int wid  = __builtin_amdgcn_readfirstlane(threadIdx.x >> 6);
    const int r0   = blockIdx.x * 64;
    const int row  = r0 + lane;

    float acc[CPW];
    #pragma unroll
    for (int j = 0; j < CPW; ++j) acc[j] = 0.f;

    for (int k0 = 0; k0 < KD; k0 += 64) {
        __syncthreads();
        for (int r = wid; r < 64; r += 4) {
            int rr = r0 + r;
            a_lds[r][lane] = (rr < M) ? A[(long)rr * KD + k0 + lane] : 0.f;
        }
        __syncthreads();
        for (int k = 0; k < 64; ++k) {
            float a = a_lds[lane][k];
            const float* wrow = W + (long)(k0 + k) * NC + wid * CPW;
            #pragma unroll
            for (int j = 0; j < CPW; ++j) acc[j] = fmaf(a, wrow[j], acc[j]);
        }
    }
    if (row < M) {
        float* crow = C + (long)row * NC + wid * CPW;
        #pragma unroll
        for (int j = 0; j < CPW; ++j) crow[j] = acc[j];
    }
}

// =====================================================================
// K4 (pass A): per augmented edge: ee = ea@we; msg = leaky(ee+xl[s]+xr[d]);
//     logits = msg . att ; atomicMax per (dst, head).  lane = edge.
// =====================================================================
template<int HEADS>
__global__ __launch_bounds__(256) void k_gat_logits(
    const float* __restrict__ eattr, const int* __restrict__ src, const int* __restrict__ dst,
    const float* __restrict__ loopa,
    const float* __restrict__ xl, const float* __restrict__ xr,
    const float* __restrict__ we, const float* __restrict__ att,
    float* __restrict__ logits, unsigned* __restrict__ mmax)
{
    constexpr int OC  = HEADS * 128;
    constexpr int CPW = OC / 4;
    __shared__ float ea_lds[64][65];
    __shared__ float p_lds[4][64];
    const int lane = threadIdx.x & 63;
    const int wid  = __builtin_amdgcn_readfirstlane(threadIdx.x >> 6);
    const long e0  = (long)blockIdx.x * 64;

    for (int r = wid; r < 64; r += 4) {
        long e = e0 + r;
        float v = 0.f;
        if (e < EA) {
            const float* ap = (e < NE) ? (eattr + e * ED) : (loopa + (e - NE) * ED);
            v = ap[lane];
        }
        ea_lds[r][lane] = v;
    }
    __syncthreads();

    const long e  = e0 + lane;
    const bool val = (e < EA);
    int s = 0, d = 0;
    if (val) { if (e < NE) { s = src[e]; d = dst[e]; } else { s = d = (int)(e - NE); } }
    const int c0 = wid * CPW;

    float acc[CPW];
    #pragma unroll
    for (int j = 0; j < CPW; ++j) acc[j] = 0.f;
    for (int k = 0; k < 64; ++k) {
        float a = ea_lds[lane][k];
        const float* wrow = we + (long)k * OC + c0;
        #pragma unroll
        for (int j = 0; j < CPW; ++j) acc[j] = fmaf(a, wrow[j], acc[j]);
    }

    const float* xlr = xl + (long)s * OC + c0;
    const float* xrr = xr + (long)d * OC + c0;
    float part = 0.f;
    #pragma unroll
    for (int j = 0; j < CPW; ++j) {
        float m = acc[j] + xlr[j] + xrr[j];
        m = (m > 0.f) ? m : 0.2f * m;                  // leaky_relu(0.2)
        part = fmaf(m, att[c0 + j], part);             // att flat over [OC]
    }
    p_lds[wid][lane] = part;
    __syncthreads();

    if (wid == 0 && val) {
        if (HEADS == 2) {
            float lg0 = p_lds[0][lane] + p_lds[1][lane];
            float lg1 = p_lds[2][lane] + p_lds[3][lane];
            logits[e * 2 + 0] = lg0;  logits[e * 2 + 1] = lg1;
            atomicMax(&mmax[(long)d * 2 + 0], fenc(lg0));
            atomicMax(&mmax[(long)d * 2 + 1], fenc(lg1));
        } else {
            float lg = p_lds[0][lane] + p_lds[1][lane] + p_lds[2][lane] + p_lds[3][lane];
            logits[e] = lg;
            atomicMax(&mmax[d], fenc(lg));
        }
    }
}

// =====================================================================
// K5 (pass B): exp(logit - max) in place; atomicAdd denom
// =====================================================================
template<int HEADS>
__global__ void k_gat_softmax_e(const int* __restrict__ dst, float* __restrict__ logits,
                                const unsigned* __restrict__ mmax, float* __restrict__ denom)
{
    long e = (long)blockIdx.x * blockDim.x + threadIdx.x;
    if (e >= EA) return;
    int d = (e < NE) ? dst[e] : (int)(e - NE);
    #pragma unroll
    for (int h = 0; h < HEADS; ++h) {
        float m  = fdec(mmax[(long)d * HEADS + h]);
        float ex = __expf(logits[e * HEADS + h] - m);
        logits[e * HEADS + h] = ex;
        atomicAdd(&denom[(long)d * HEADS + h], ex);
    }
}

// =====================================================================
// K6 (pass C): hacc[dst] += xl[src] * alpha   (wave per edge)
// =====================================================================
template<int HEADS>
__global__ __launch_bounds__(256) void k_gat_aggregate(
    const int* __restrict__ src, const int* __restrict__ dst,
    const float* __restrict__ xl, const float* __restrict__ expv,
    const float* __restrict__ denom, float* __restrict__ hacc)
{
    constexpr int OC  = HEADS * 128;
    constexpr int CPL = OC / 64;
    const int lane = threadIdx.x & 63;
    long e = (long)blockIdx.x * 4 + (threadIdx.x >> 6);
    if (e >= EA) return;
    int s, d;
    if (e < NE) { s = src[e]; d = dst[e]; } else { s = d = (int)(e - NE); }
    const int c = lane * CPL;
    const int h = c >> 7;
    float alpha = expv[e * HEADS + h] / (denom[(long)d * HEADS + h] + 1e-16f);
    const float* xrow = xl + (long)s * OC + c;
    float* orow = hacc + (long)d * OC + c;
    #pragma unroll
    for (int j = 0; j < CPL; ++j) atomicAdd(&orow[j], xrow[j] * alpha);
}

// =====================================================================
// K7: head-mean + bias -> LayerNorm -> ELU   (wave per node)
// =====================================================================
template<int HEADS>
__global__ __launch_bounds__(256) void k_node_ln(
    const float* __restrict__ hacc, const float* __restrict__ bias,
    const float* __restrict__ g, const float* __restrict__ b,
    float* __restrict__ hout)
{
    const int lane = threadIdx.x & 63;
    int n = blockIdx.x * 4 + (threadIdx.x >> 6);
    if (n >= NN) return;
    const float* row = hacc + (long)n * HEADS * 128;
    float v[2];
    #pragma unroll
    for (int q = 0; q < 2; ++q) {
        int c = lane + q * 64;
        float x = (HEADS == 2) ? 0.5f * (row[c] + row[128 + c]) : row[c];
        v[q] = x + bias[c];
    }
    float sum = v[0] + v[1];
    #pragma unroll
    for (int off = 32; off; off >>= 1) sum += __shfl_xor(sum, off);
    float mu = sum * (1.f / 128.f);
    float d0 = v[0] - mu, d1 = v[1] - mu;
    float vs = d0 * d0 + d1 * d1;
    #pragma unroll
    for (int off = 32; off; off >>= 1) vs += __shfl_xor(vs, off);
    float rstd = rsqrtf(vs * (1.f / 128.f) + 1e-5f);
    #pragma unroll
    for (int q = 0; q < 2; ++q) {
        int c = lane + q * 64;
        float y = (v[q] - mu) * rstd * g[c] + b[c];
        hout[(long)n * 128 + c] = (y > 0.f) ? y : (__expf(y) - 1.f);  // ELU
    }
}

// =====================================================================
// K8: fused classifier  rep=[h2[s],h2[d],ea] -> 320->128->64->1
//     lane = edge, 64 edges/block, 4 waves x 32 cols (z1), x16 (z2)
// =====================================================================
__global__ __launch_bounds__(256) void k_classifier(
    const float* __restrict__ h2, const int* __restrict__ src, const int* __restrict__ dst,
    const float* __restrict__ eattr,
    const float* __restrict__ c1w, const float* __restrict__ c1b,
    const float* __restrict__ c2w, const float* __restrict__ c2b,
    const float* __restrict__ c3w, const float* __restrict__ c3b,
    float* __restrict__ out)
{
    __shared__ float smem[128 * 65];                    // rep chunk [64][65] then z1 [128][65]
    __shared__ float p_lds[4][64];
    const int lane = threadIdx.x & 63;
    const int wid  = __builtin_amdgcn_readfirstlane(threadIdx.x >> 6);
    const long e0  = (long)blockIdx.x * 64;
    const long e   = e0 + lane;
    const bool val = (e < NE);
    const int c0   = wid * 32;

    float acc[32];
    #pragma unroll
    for (int j = 0; j < 32; ++j) acc[j] = c1b[c0 + j];

    for (int ch = 0; ch < 5; ++ch) {
        __syncthreads();
        for (int rr = wid; rr < 64; rr += 4) {
            long ee = e0 + rr;
            float v = 0.f;
            if (ee < NE) {
                const float* p;
                if      (ch == 0) p = h2 + (long)src[ee] * 128;
                else if (ch == 1) p = h2 + (long)src[ee] * 128 + 64;
                else if (ch == 2) p = h2 + (long)dst[ee] * 128;
                else if (ch == 3) p = h2 + (long)dst[ee] * 128 + 64;
                else              p = eattr + ee * ED;
                v = p[lane];
            }
            smem[rr * 65 + lane] = v;
        }
        __syncthreads();
        const float* wbase = c1w + (long)ch * 64 * 128 + c0;
        for (int k = 0; k < 64; ++k) {
            float a = smem[lane * 65 + k];
            const float* wrow = wbase + (long)k * 128;
            #pragma unroll
            for (int j = 0; j < 32; ++j) acc[j] = fmaf(a, wrow[j], acc[j]);
        }
    }
    __syncthreads();
    #pragma unroll
    for (int j = 0; j < 32; ++j) smem[(c0 + j) * 65 + lane] = fmaxf(acc[j], 0.f);  // z1^T
    __syncthreads();

    float acc2[16];
    #pragma unroll
    for (int j = 0; j < 16; ++j) acc2[j] = c2b[wid * 16 + j];
    for (int k = 0; k < 128; ++k) {
        float a = smem[k * 65 + lane];
        const float* wrow = c2w + (long)k * 64 + wid * 16;
        #pragma unroll
        for (int j = 0; j < 16; ++j) acc2[j] = fmaf(a, wrow[j], acc2[j]);
    }
    float part = 0.f;
    #pragma unroll
    for (int j = 0; j < 16; ++j) part = fmaf(fmaxf(acc2[j], 0.f), c3w[wid * 16 + j], part);
    p_lds[wid][lane] = part;
    __syncthreads();
    if (wid == 0 && val)
        out[e] = p_lds[0][lane] + p_lds[1][lane] + p_lds[2][lane] + p_lds[3][lane] + c3b[0];
}

// =====================================================================
extern "C" void kernel_launch(void* const* d_in, const int* in_sizes, int n_in,
                              void* d_out, int out_size, void* d_ws, size_t ws_size,
                              hipStream_t stream)
{
    const int*   edge_index = (const int*)  d_in[1];
    const float* edge_attr  = (const float*)d_in[2];
    const float* ep_w  = (const float*)d_in[3];
    const float* ep_b  = (const float*)d_in[4];
    const float* g1_wl = (const float*)d_in[5];
    const float* g1_wr = (const float*)d_in[6];
    const float* g1_we = (const float*)d_in[7];
    const float* g1_att= (const float*)d_in[8];
    const float* g1_b  = (const float*)d_in[9];
    const float* n1_g  = (const float*)d_in[10];
    const float* n1_b  = (const float*)d_in[11];
    const float* g2_wl = (const float*)d_in[12];
    const float* g2_wr = (const float*)d_in[13];
    const float* g2_we = (const float*)d_in[14];
    const float* g2_att= (const float*)d_in[15];
    const float* g2_b  = (const float*)d_in[16];
    const float* n2_g  = (const float*)d_in[17];
    const float* n2_b  = (const float*)d_in[18];
    const float* c1_w  = (const float*)d_in[19];
    const float* c1_b  = (const float*)d_in[20];
    const float* c2_w  = (const float*)d_in[21];
    const float* c2_b  = (const float*)d_in[22];
    const float* c3_w  = (const float*)d_in[23];
    const float* c3_b  = (const float*)d_in[24];
    const int* src = edge_index;
    const int* dst = edge_index + NE;

    // ---- workspace layout (floats), ~250 MB with reuse ----
    float* ws = (float*)d_ws;
    size_t o = 0;
    float*    xo    = ws + o; o += (size_t)NN * 128;   // later reused: xl2
    float*    xi    = ws + o; o += (size_t)NN * 128;   // later reused: xr2
    float*    loopa = ws + o; o += (size_t)NN * 64;
    float*    cs    = ws + o; o += NN;
    float*    cd    = ws + o; o += NN;
    unsigned* mmax  = (unsigned*)(ws + o); o += (size_t)NN * 2;   // layer2 reuses
    float*    denom = ws + o; o += (size_t)NN * 2;                // layer2 reuses
    const size_t zeroN = o;
    float* x_input = ws + o; o += (size_t)NN * 256;    // later reused: h1acc
    float* xl1     = ws + o; o += (size_t)NN * 256;    // first NN*128 reused: h2acc
    float* xr1     = ws + o; o += (size_t)NN * 256;    // first NN*128 reused: h2
    float* logits  = ws + o; o += (size_t)EA * 2;      // layer2 reuses first EA
    float* h1      = ws + o; o += (size_t)NN * 128;

    float* h1acc = x_input;
    float* h2acc = xl1;
    float* h2    = xr1;
    float* xl2   = xo;
    float* xr2   = xi;

    // ---- stage 0: zero accumulators ----
    hipMemsetAsync(d_ws, 0, zeroN * sizeof(float), stream);

    // ---- stage 1: edge projection + scatter means ----
    k_edge_proj<<<(NE + 63) / 64, 256, 0, stream>>>(edge_attr, src, dst, ep_w, ep_b, xo, xi, loopa, cs, cd);
    k_finalize<<<(int)(((long)NN * 128 + 255) / 256), 256, 0, stream>>>(xo, xi, cs, cd, x_input, loopa);

    // ---- GAT layer 1 (heads=2) ----
    k_gemm<256, 256><<<(NN + 63) / 64, 256, 0, stream>>>(x_input, g1_wl, xl1, NN);
    k_gemm<256, 256><<<(NN + 63) / 64, 256, 0, stream>>>(x_input, g1_wr, xr1, NN);
    k_gat_logits<2><<<(int)((EA + 63) / 64), 256, 0, stream>>>(edge_attr, src, dst, loopa, xl1, xr1, g1_we, g1_att, logits, mmax);
    k_gat_softmax_e<2><<<(int)((EA + 255) / 256), 256, 0, stream>>>(dst, logits, mmax, denom);
    hipMemsetAsync(h1acc, 0, (size_t)NN * 256 * sizeof(float), stream);
    k_gat_aggregate<2><<<(int)((EA + 3) / 4), 256, 0, stream>>>(src, dst, xl1, logits, denom, h1acc);
    k_node_ln<2><<<(NN + 3) / 4, 256, 0, stream>>>(h1acc, g1_b, n1_g, n1_b, h1);

    // ---- GAT layer 2 (heads=1) ----
    hipMemsetAsync(mmax, 0, (size_t)NN * 4 * sizeof(float), stream);           // mmax + denom
    hipMemsetAsync(h2acc, 0, (size_t)NN * 128 * sizeof(float), stream);
    k_gemm<128, 128><<<(NN + 63) / 64, 256, 0, stream>>>(h1, g2_wl, xl2, NN);
    k_gemm<128, 128><<<(NN + 63) / 64, 256, 0, stream>>>(h1, g2_wr, xr2, NN);
    k_gat_logits<1><<<(int)((EA + 63) / 64), 256, 0, stream>>>(edge_attr, src, dst, loopa, xl2, xr2, g2_we, g2_att, logits, mmax);
    k_gat_softmax_e<1><<<(int)((EA + 255) / 256), 256, 0, stream>>>(dst, logits, mmax, denom);
    k_gat_aggregate<1><<<(int)((EA + 3) / 4), 256, 0, stream>>>(src, dst, xl2, logits, denom, h2acc);
    k_node_ln<1><<<(NN + 3) / 4, 256, 0, stream>>>(h2acc, g2_b, n2_g, n2_b, h2);

    // ---- classifier ----
    k_classifier<<<(NE + 63) / 64, 256, 0, stream>>>(h2, src, dst, edge_attr,
                                                     c1_w, c1_b, c2_w, c2_b, c3_w, c3_b,
                                                     (float*)d_out);
}

// Round 2
// 3140.318 us; speedup vs baseline: 4.7819x; 4.7819x over previous
//
#include <hip/hip_runtime.h>

// ---- problem constants ----
constexpr int   NN  = 50000;            // nodes
constexpr int   NE  = 600000;           // edges
constexpr int   EA  = NE + NN;          // augmented edges (self loops appended)
constexpr int   ND  = 128;              // node dim
constexpr int   ED  = 64;               // edge dim
constexpr int   HD  = 128;              // hidden dim

// =====================================================================
// CSR build: histogram -> prefix scan -> scatter
// =====================================================================
__global__ void k_hist(const int* __restrict__ src, const int* __restrict__ dst,
                       int* __restrict__ cntS, int* __restrict__ cntD)
{
    int e = blockIdx.x * 256 + threadIdx.x;
    if (e >= NE) return;
    atomicAdd(&cntS[src[e]], 1);
    atomicAdd(&cntD[dst[e]], 1);
}

__global__ __launch_bounds__(1024) void k_scan(
    const int* __restrict__ cntS, const int* __restrict__ cntD,
    int* __restrict__ rpS, int* __restrict__ rpD,
    int* __restrict__ curS, int* __restrict__ curD)
{
    __shared__ int part[1024];
    const int tid = threadIdx.x;
    constexpr int CH = (NN + 1023) / 1024;
    for (int pass = 0; pass < 2; ++pass) {
        const int* cnt = pass ? cntD : cntS;
        int* rp  = pass ? rpD  : rpS;
        int* cur = pass ? curD : curS;
        int i0 = tid * CH, i1 = (i0 + CH < NN) ? i0 + CH : NN;
        int ls = 0;
        for (int i = i0; i < i1; ++i) ls += cnt[i];
        part[tid] = ls;
        __syncthreads();
        for (int off = 1; off < 1024; off <<= 1) {
            int v = (tid >= off) ? part[tid - off] : 0;
            __syncthreads();
            part[tid] += v;
            __syncthreads();
        }
        int run = tid ? part[tid - 1] : 0;
        for (int i = i0; i < i1; ++i) { rp[i] = run; cur[i] = run; run += cnt[i]; }
        if (tid == 1023) rp[NN] = run;
        __syncthreads();
    }
}

__global__ void k_scatter(const int* __restrict__ src, const int* __restrict__ dst,
                          int* __restrict__ curS, int* __restrict__ curD,
                          int* __restrict__ eidS, int* __restrict__ eidD)
{
    int e = blockIdx.x * 256 + threadIdx.x;
    if (e >= NE) return;
    eidS[atomicAdd(&curS[src[e]], 1)] = e;
    eidD[atomicAdd(&curD[dst[e]], 1)] = e;
}

// =====================================================================
// K1: node-centric edge-projection means.
//   x_out[n] = mean_{e: src=n} relu(ea[e]@W+b)   (via src-CSR)
//   x_in [n] = mean_{e: dst=n} relu(ea[e]@W+b)   (via dst-CSR)
//   loopa[n] = mean_{e: dst=n} ea[e]
// Wave per node; W held in 128 VGPRs/lane; ea row via wave-uniform s_load.
// =====================================================================
__global__ __launch_bounds__(256) void k_node_inputs(
    const float* __restrict__ eattr,
    const int* __restrict__ rpS, const int* __restrict__ eidS,
    const int* __restrict__ rpD, const int* __restrict__ eidD,
    const float* __restrict__ ep_w, const float* __restrict__ ep_b,
    float* __restrict__ x_input, float* __restrict__ loopa)
{
    const int lane = threadIdx.x & 63;
    const int n = blockIdx.x * 4 + (threadIdx.x >> 6);
    if (n >= NN) return;

    float w0r[64], w1r[64];
    #pragma unroll
    for (int k = 0; k < 64; ++k) {
        w0r[k] = ep_w[k * ND + lane];
        w1r[k] = ep_w[k * ND + 64 + lane];
    }
    const float bb0 = ep_b[lane], bb1 = ep_b[64 + lane];

    float aO0 = 0.f, aO1 = 0.f;
    const int s0 = rpS[n], s1 = rpS[n + 1];
    for (int i = s0; i < s1; ++i) {
        const int e = __builtin_amdgcn_readfirstlane(eidS[i]);
        const float* ea = eattr + (long)e * ED;
        float d0 = bb0, d1 = bb1;
        #pragma unroll
        for (int k = 0; k < 64; ++k) {
            float a = ea[k];                       // uniform -> s_load
            d0 = fmaf(a, w0r[k], d0);
            d1 = fmaf(a, w1r[k], d1);
        }
        aO0 += fmaxf(d0, 0.f);
        aO1 += fmaxf(d1, 0.f);
    }

    float aI0 = 0.f, aI1 = 0.f, la = 0.f;
    const int d0i = rpD[n], d1i = rpD[n + 1];
    for (int i = d0i; i < d1i; ++i) {
        const int e = __builtin_amdgcn_readfirstlane(eidD[i]);
        const float* ea = eattr + (long)e * ED;
        la += ea[lane];                            // lane-varying vector load
        float d0 = bb0, d1 = bb1;
        #pragma unroll
        for (int k = 0; k < 64; ++k) {
            float a = ea[k];
            d0 = fmaf(a, w0r[k], d0);
            d1 = fmaf(a, w1r[k], d1);
        }
        aI0 += fmaxf(d0, 0.f);
        aI1 += fmaxf(d1, 0.f);
    }

    const float invS = 1.f / (float)((s1 - s0) > 1 ? (s1 - s0) : 1);
    const float invD = 1.f / (float)((d1i - d0i) > 1 ? (d1i - d0i) : 1);
    float* xrow = x_input + (long)n * 256;
    xrow[lane]        = aO0 * invS;
    xrow[64 + lane]   = aO1 * invS;
    xrow[128 + lane]  = aI0 * invD;
    xrow[192 + lane]  = aI1 * invD;
    loopa[(long)n * ED + lane] = la * invD;
}

// =====================================================================
// K3: generic dense GEMM  C[M,NC] = A[M,KD] @ W[KD,NC]
// =====================================================================
template<int KD, int NC>
__global__ __launch_bounds__(256) void k_gemm(const float* __restrict__ A,
                                              const float* __restrict__ W,
                                              float* __restrict__ C, int M)
{
    constexpr int CPW = NC / 4;
    __shared__ float a_lds[64][65];
    const int lane = threadIdx.x & 63;
    const int wid  = __builtin_amdgcn_readfirstlane(threadIdx.x >> 6);
    const int r0   = blockIdx.x * 64;
    const int row  = r0 + lane;

    float acc[CPW];
    #pragma unroll
    for (int j = 0; j < CPW; ++j) acc[j] = 0.f;

    for (int k0 = 0; k0 < KD; k0 += 64) {
        __syncthreads();
        for (int r = wid; r < 64; r += 4) {
            int rr = r0 + r;
            a_lds[r][lane] = (rr < M) ? A[(long)rr * KD + k0 + lane] : 0.f;
        }
        __syncthreads();
        for (int k = 0; k < 64; ++k) {
            float a = a_lds[lane][k];
            const float* wrow = W + (long)(k0 + k) * NC + wid * CPW;
            #pragma unroll
            for (int j = 0; j < CPW; ++j) acc[j] = fmaf(a, wrow[j], acc[j]);
        }
    }
    if (row < M) {
        float* crow = C + (long)row * NC + wid * CPW;
        #pragma unroll
        for (int j = 0; j < CPW; ++j) crow[j] = acc[j];
    }
}

// =====================================================================
// K4: per augmented edge: ee = ea@we; msg = leaky(ee+xl[s]+xr[d]);
//     logits = msg . att  (stored, no atomics)
// =====================================================================
template<int HEADS>
__global__ __launch_bounds__(256) void k_gat_logits(
    const float* __restrict__ eattr, const int* __restrict__ src, const int* __restrict__ dst,
    const float* __restrict__ loopa,
    const float* __restrict__ xl, const float* __restrict__ xr,
    const float* __restrict__ we, const float* __restrict__ att,
    float* __restrict__ logits)
{
    constexpr int OC  = HEADS * 128;
    constexpr int CPW = OC / 4;
    __shared__ float ea_lds[64][65];
    __shared__ float p_lds[4][64];
    const int lane = threadIdx.x & 63;
    const int wid  = __builtin_amdgcn_readfirstlane(threadIdx.x >> 6);
    const long e0  = (long)blockIdx.x * 64;

    for (int r = wid; r < 64; r += 4) {
        long e = e0 + r;
        float v = 0.f;
        if (e < EA) {
            const float* ap = (e < NE) ? (eattr + e * ED) : (loopa + (e - NE) * ED);
            v = ap[lane];
        }
        ea_lds[r][lane] = v;
    }
    __syncthreads();

    const long e  = e0 + lane;
    const bool val = (e < EA);
    int s = 0, d = 0;
    if (val) { if (e < NE) { s = src[e]; d = dst[e]; } else { s = d = (int)(e - NE); } }
    const int c0 = wid * CPW;

    float acc[CPW];
    #pragma unroll
    for (int j = 0; j < CPW; ++j) acc[j] = 0.f;
    for (int k = 0; k < 64; ++k) {
        float a = ea_lds[lane][k];
        const float* wrow = we + (long)k * OC + c0;
        #pragma unroll
        for (int j = 0; j < CPW; ++j) acc[j] = fmaf(a, wrow[j], acc[j]);
    }

    const float* xlr = xl + (long)s * OC + c0;
    const float* xrr = xr + (long)d * OC + c0;
    float part = 0.f;
    #pragma unroll
    for (int j = 0; j < CPW; ++j) {
        float m = acc[j] + xlr[j] + xrr[j];
        m = (m > 0.f) ? m : 0.2f * m;                  // leaky_relu(0.2)
        part = fmaf(m, att[c0 + j], part);
    }
    p_lds[wid][lane] = part;
    __syncthreads();

    if (wid == 0 && val) {
        if (HEADS == 2) {
            logits[e * 2 + 0] = p_lds[0][lane] + p_lds[1][lane];
            logits[e * 2 + 1] = p_lds[2][lane] + p_lds[3][lane];
        } else {
            logits[e] = p_lds[0][lane] + p_lds[1][lane] + p_lds[2][lane] + p_lds[3][lane];
        }
    }
}

// =====================================================================
// K5: fused segment softmax + aggregation + head-mean + LN + ELU.
//     Wave per dst node, gather via dst-CSR (+ implicit self loop).
// =====================================================================
template<int HEADS>
__global__ __launch_bounds__(256) void k_gat_reduce(
    const int* __restrict__ rpD, const int* __restrict__ eidD,
    const int* __restrict__ src,
    const float* __restrict__ xl, const float* __restrict__ logits,
    const float* __restrict__ bias, const float* __restrict__ g, const float* __restrict__ b,
    float* __restrict__ hout)
{
    constexpr int OC = HEADS * 128;
    const int lane = threadIdx.x & 63;
    const int n = blockIdx.x * 4 + (threadIdx.x >> 6);
    if (n >= NN) return;

    const int base = rpD[n];
    const int deg  = rpD[n + 1] - base;
    const int nea  = deg + 1;                          // + self loop

    // pass 1: segment max (lane-parallel)
    float m0 = -1e30f, m1 = -1e30f;
    for (int i = lane; i < nea; i += 64) {
        int e = (i < deg) ? eidD[base + i] : (NE + n);
        m0 = fmaxf(m0, logits[(long)e * HEADS + 0]);
        if (HEADS == 2) m1 = fmaxf(m1, logits[(long)e * HEADS + 1]);
    }
    #pragma unroll
    for (int off = 32; off; off >>= 1) {
        m0 = fmaxf(m0, __shfl_xor(m0, off));
        if (HEADS == 2) m1 = fmaxf(m1, __shfl_xor(m1, off));
    }

    // pass 2: denom (lane-parallel)
    float s0 = 0.f, s1 = 0.f;
    for (int i = lane; i < nea; i += 64) {
        int e = (i < deg) ? eidD[base + i] : (NE + n);
        s0 += __expf(logits[(long)e * HEADS + 0] - m0);
        if (HEADS == 2) s1 += __expf(logits[(long)e * HEADS + 1] - m1);
    }
    #pragma unroll
    for (int off = 32; off; off >>= 1) {
        s0 += __shfl_xor(s0, off);
        if (HEADS == 2) s1 += __shfl_xor(s1, off);
    }
    const float inv0 = 1.f / (s0 + 1e-16f);
    const float inv1 = 1.f / (s1 + 1e-16f);

    // pass 3: weighted aggregation (edges serial, cols lane-parallel)
    float a0 = 0.f, a1 = 0.f, a2 = 0.f, a3 = 0.f;
    for (int i = 0; i < nea; ++i) {
        const int e  = __builtin_amdgcn_readfirstlane((i < deg) ? eidD[base + i] : (NE + n));
        const int sN = (e < NE) ? src[e] : (e - NE);   // uniform -> s_load
        const float w0 = __expf(logits[(long)e * HEADS + 0] - m0) * inv0;
        const float* xrow = xl + (long)sN * OC;
        a0 = fmaf(xrow[lane],      w0, a0);
        a1 = fmaf(xrow[64 + lane], w0, a1);
        if (HEADS == 2) {
            const float w1 = __expf(logits[(long)e * HEADS + 1] - m1) * inv1;
            a2 = fmaf(xrow[128 + lane], w1, a2);
            a3 = fmaf(xrow[192 + lane], w1, a3);
        }
    }

    // epilogue: head mean + bias -> LN -> ELU
    float v0, v1;
    if (HEADS == 2) { v0 = 0.5f * (a0 + a2); v1 = 0.5f * (a1 + a3); }
    else            { v0 = a0;               v1 = a1; }
    v0 += bias[lane];
    v1 += bias[64 + lane];

    float sum = v0 + v1;
    #pragma unroll
    for (int off = 32; off; off >>= 1) sum += __shfl_xor(sum, off);
    const float mu = sum * (1.f / 128.f);
    const float q0 = v0 - mu, q1 = v1 - mu;
    float vs = q0 * q0 + q1 * q1;
    #pragma unroll
    for (int off = 32; off; off >>= 1) vs += __shfl_xor(vs, off);
    const float rstd = rsqrtf(vs * (1.f / 128.f) + 1e-5f);

    float y0 = q0 * rstd * g[lane]      + b[lane];
    float y1 = q1 * rstd * g[64 + lane] + b[64 + lane];
    hout[(long)n * 128 + lane]      = (y0 > 0.f) ? y0 : (__expf(y0) - 1.f);
    hout[(long)n * 128 + 64 + lane] = (y1 > 0.f) ? y1 : (__expf(y1) - 1.f);
}

// =====================================================================
// K8: fused classifier  rep=[h2[s],h2[d],ea] -> 320->128->64->1
// =====================================================================
__global__ __launch_bounds__(256) void k_classifier(
    const float* __restrict__ h2, const int* __restrict__ src, const int* __restrict__ dst,
    const float* __restrict__ eattr,
    const float* __restrict__ c1w, const float* __restrict__ c1b,
    const float* __restrict__ c2w, const float* __restrict__ c2b,
    const float* __restrict__ c3w, const float* __restrict__ c3b,
    float* __restrict__ out)
{
    __shared__ float smem[128 * 65];
    __shared__ float p_lds[4][64];
    const int lane = threadIdx.x & 63;
    const int wid  = __builtin_amdgcn_readfirstlane(threadIdx.x >> 6);
    const long e0  = (long)blockIdx.x * 64;
    const long e   = e0 + lane;
    const bool val = (e < NE);
    const int c0   = wid * 32;

    float acc[32];
    #pragma unroll
    for (int j = 0; j < 32; ++j) acc[j] = c1b[c0 + j];

    for (int ch = 0; ch < 5; ++ch) {
        __syncthreads();
        for (int rr = wid; rr < 64; rr += 4) {
            long ee = e0 + rr;
            float v = 0.f;
            if (ee < NE) {
                const float* p;
                if      (ch == 0) p = h2 + (long)src[ee] * 128;
                else if (ch == 1) p = h2 + (long)src[ee] * 128 + 64;
                else if (ch == 2) p = h2 + (long)dst[ee] * 128;
                else if (ch == 3) p = h2 + (long)dst[ee] * 128 + 64;
                else              p = eattr + ee * ED;
                v = p[lane];
            }
            smem[rr * 65 + lane] = v;
        }
        __syncthreads();
        const float* wbase = c1w + (long)ch * 64 * 128 + c0;
        for (int k = 0; k < 64; ++k) {
            float a = smem[lane * 65 + k];
            const float* wrow = wbase + (long)k * 128;
            #pragma unroll
            for (int j = 0; j < 32; ++j) acc[j] = fmaf(a, wrow[j], acc[j]);
        }
    }
    __syncthreads();
    #pragma unroll
    for (int j = 0; j < 32; ++j) smem[(c0 + j) * 65 + lane] = fmaxf(acc[j], 0.f);  // z1^T
    __syncthreads();

    float acc2[16];
    #pragma unroll
    for (int j = 0; j < 16; ++j) acc2[j] = c2b[wid * 16 + j];
    for (int k = 0; k < 128; ++k) {
        float a = smem[k * 65 + lane];
        const float* wrow = c2w + (long)k * 64 + wid * 16;
        #pragma unroll
        for (int j = 0; j < 16; ++j) acc2[j] = fmaf(a, wrow[j], acc2[j]);
    }
    float part = 0.f;
    #pragma unroll
    for (int j = 0; j < 16; ++j) part = fmaf(fmaxf(acc2[j], 0.f), c3w[wid * 16 + j], part);
    p_lds[wid][lane] = part;
    __syncthreads();
    if (wid == 0 && val)
        out[e] = p_lds[0][lane] + p_lds[1][lane] + p_lds[2][lane] + p_lds[3][lane] + c3b[0];
}

// =====================================================================
extern "C" void kernel_launch(void* const* d_in, const int* in_sizes, int n_in,
                              void* d_out, int out_size, void* d_ws, size_t ws_size,
                              hipStream_t stream)
{
    const int*   edge_index = (const int*)  d_in[1];
    const float* edge_attr  = (const float*)d_in[2];
    const float* ep_w  = (const float*)d_in[3];
    const float* ep_b  = (const float*)d_in[4];
    const float* g1_wl = (const float*)d_in[5];
    const float* g1_wr = (const float*)d_in[6];
    const float* g1_we = (const float*)d_in[7];
    const float* g1_att= (const float*)d_in[8];
    const float* g1_b  = (const float*)d_in[9];
    const float* n1_g  = (const float*)d_in[10];
    const float* n1_b  = (const float*)d_in[11];
    const float* g2_wl = (const float*)d_in[12];
    const float* g2_wr = (const float*)d_in[13];
    const float* g2_we = (const float*)d_in[14];
    const float* g2_att= (const float*)d_in[15];
    const float* g2_b  = (const float*)d_in[16];
    const float* n2_g  = (const float*)d_in[17];
    const float* n2_b  = (const float*)d_in[18];
    const float* c1_w  = (const float*)d_in[19];
    const float* c1_b  = (const float*)d_in[20];
    const float* c2_w  = (const float*)d_in[21];
    const float* c2_b  = (const float*)d_in[22];
    const float* c3_w  = (const float*)d_in[23];
    const float* c3_b  = (const float*)d_in[24];
    const int* src = edge_index;
    const int* dst = edge_index + NE;

    // ---- workspace layout ----
    char* wsb = (char*)d_ws;
    size_t o = 0;
    auto alloc = [&](size_t bytes) { void* p = wsb + o; o += (bytes + 255) & ~(size_t)255; return p; };
    int* cntS = (int*)alloc(NN * 4);          // cntS+cntD must stay first (one memset)
    int* cntD = (int*)alloc(NN * 4);
    int* curS = (int*)alloc(NN * 4);
    int* curD = (int*)alloc(NN * 4);
    int* rpS  = (int*)alloc((NN + 1) * 4);
    int* rpD  = (int*)alloc((NN + 1) * 4);
    int* eidS = (int*)alloc((size_t)NE * 4);
    int* eidD = (int*)alloc((size_t)NE * 4);
    float* loopa   = (float*)alloc((size_t)NN * 64 * 4);
    float* x_input = (float*)alloc((size_t)NN * 256 * 4);   // reused: h2
    float* xl1     = (float*)alloc((size_t)NN * 256 * 4);   // reused: xl2
    float* xr1     = (float*)alloc((size_t)NN * 256 * 4);   // reused: xr2
    float* logits  = (float*)alloc((size_t)EA * 2 * 4);
    float* h1      = (float*)alloc((size_t)NN * 128 * 4);
    float* xl2 = xl1;
    float* xr2 = xr1;
    float* h2  = x_input;

    // ---- CSR build ----
    hipMemsetAsync(d_ws, 0, 2 * ((NN * 4 + 255) & ~255), stream);   // cntS + cntD
    k_hist<<<(NE + 255) / 256, 256, 0, stream>>>(src, dst, cntS, cntD);
    k_scan<<<1, 1024, 0, stream>>>(cntS, cntD, rpS, rpD, curS, curD);
    k_scatter<<<(NE + 255) / 256, 256, 0, stream>>>(src, dst, curS, curD, eidS, eidD);

    // ---- stage 1: node input features (no atomics) ----
    k_node_inputs<<<(NN + 3) / 4, 256, 0, stream>>>(edge_attr, rpS, eidS, rpD, eidD,
                                                    ep_w, ep_b, x_input, loopa);

    // ---- GAT layer 1 (heads=2) ----
    k_gemm<256, 256><<<(NN + 63) / 64, 256, 0, stream>>>(x_input, g1_wl, xl1, NN);
    k_gemm<256, 256><<<(NN + 63) / 64, 256, 0, stream>>>(x_input, g1_wr, xr1, NN);
    k_gat_logits<2><<<(EA + 63) / 64, 256, 0, stream>>>(edge_attr, src, dst, loopa, xl1, xr1, g1_we, g1_att, logits);
    k_gat_reduce<2><<<(NN + 3) / 4, 256, 0, stream>>>(rpD, eidD, src, xl1, logits, g1_b, n1_g, n1_b, h1);

    // ---- GAT layer 2 (heads=1) ----
    k_gemm<128, 128><<<(NN + 63) / 64, 256, 0, stream>>>(h1, g2_wl, xl2, NN);
    k_gemm<128, 128><<<(NN + 63) / 64, 256, 0, stream>>>(h1, g2_wr, xr2, NN);
    k_gat_logits<1><<<(EA + 63) / 64, 256, 0, stream>>>(edge_attr, src, dst, loopa, xl2, xr2, g2_we, g2_att, logits);
    k_gat_reduce<1><<<(NN + 3) / 4, 256, 0, stream>>>(rpD, eidD, src, xl2, logits, g2_b, n2_g, n2_b, h2);

    // ---- classifier ----
    k_classifier<<<(NE + 63) / 64, 256, 0, stream>>>(h2, src, dst, edge_attr,
                                                     c1_w, c1_b, c2_w, c2_b, c3_w, c3_b,
                                                     (float*)d_out);
}

// Round 3
// 2641.576 us; speedup vs baseline: 5.6847x; 1.1888x over previous
//
#include <hip/hip_runtime.h>

// ---- problem constants ----
constexpr int   NN  = 50000;            // nodes
constexpr int   NE  = 600000;           // edges
constexpr int   EA  = NE + NN;          // augmented edges (self loops appended)
constexpr int   ND  = 128;              // node dim
constexpr int   ED  = 64;              // edge dim
constexpr int   HD  = 128;              // hidden dim

// =====================================================================
// CSR build: histogram -> prefix scan -> scatter
// =====================================================================
__global__ void k_hist(const int* __restrict__ src, const int* __restrict__ dst,
                       int* __restrict__ cntS, int* __restrict__ cntD)
{
    int e = blockIdx.x * 256 + threadIdx.x;
    if (e >= NE) return;
    atomicAdd(&cntS[src[e]], 1);
    atomicAdd(&cntD[dst[e]], 1);
}

__global__ __launch_bounds__(1024) void k_scan(
    const int* __restrict__ cntS, const int* __restrict__ cntD,
    int* __restrict__ rpS, int* __restrict__ rpD,
    int* __restrict__ curS, int* __restrict__ curD)
{
    __shared__ int part[1024];
    const int tid = threadIdx.x;
    constexpr int CH = (NN + 1023) / 1024;
    for (int pass = 0; pass < 2; ++pass) {
        const int* cnt = pass ? cntD : cntS;
        int* rp  = pass ? rpD  : rpS;
        int* cur = pass ? curD : curS;
        int i0 = tid * CH, i1 = (i0 + CH < NN) ? i0 + CH : NN;
        int ls = 0;
        for (int i = i0; i < i1; ++i) ls += cnt[i];
        part[tid] = ls;
        __syncthreads();
        for (int off = 1; off < 1024; off <<= 1) {
            int v = (tid >= off) ? part[tid - off] : 0;
            __syncthreads();
            part[tid] += v;
            __syncthreads();
        }
        int run = tid ? part[tid - 1] : 0;
        for (int i = i0; i < i1; ++i) { rp[i] = run; cur[i] = run; run += cnt[i]; }
        if (tid == 1023) rp[NN] = run;
        __syncthreads();
    }
}

__global__ void k_scatter(const int* __restrict__ src, const int* __restrict__ dst,
                          int* __restrict__ curS, int* __restrict__ curD,
                          int* __restrict__ eidS, int* __restrict__ eidD)
{
    int e = blockIdx.x * 256 + threadIdx.x;
    if (e >= NE) return;
    eidS[atomicAdd(&curS[src[e]], 1)] = e;
    eidD[atomicAdd(&curD[dst[e]], 1)] = e;
}

// =====================================================================
// K1: node-centric edge-projection means (no atomics).
// =====================================================================
__global__ __launch_bounds__(256) void k_node_inputs(
    const float* __restrict__ eattr,
    const int* __restrict__ rpS, const int* __restrict__ eidS,
    const int* __restrict__ rpD, const int* __restrict__ eidD,
    const float* __restrict__ ep_w, const float* __restrict__ ep_b,
    float* __restrict__ x_input, float* __restrict__ loopa)
{
    const int lane = threadIdx.x & 63;
    const int n = blockIdx.x * 4 + (threadIdx.x >> 6);
    if (n >= NN) return;

    float w0r[64], w1r[64];
    #pragma unroll
    for (int k = 0; k < 64; ++k) {
        w0r[k] = ep_w[k * ND + lane];
        w1r[k] = ep_w[k * ND + 64 + lane];
    }
    const float bb0 = ep_b[lane], bb1 = ep_b[64 + lane];

    float aO0 = 0.f, aO1 = 0.f;
    const int s0 = rpS[n], s1 = rpS[n + 1];
    for (int i = s0; i < s1; ++i) {
        const int e = __builtin_amdgcn_readfirstlane(eidS[i]);
        const float* ea = eattr + (long)e * ED;
        float d0 = bb0, d1 = bb1;
        #pragma unroll
        for (int k = 0; k < 64; ++k) {
            float a = ea[k];                       // uniform -> s_load
            d0 = fmaf(a, w0r[k], d0);
            d1 = fmaf(a, w1r[k], d1);
        }
        aO0 += fmaxf(d0, 0.f);
        aO1 += fmaxf(d1, 0.f);
    }

    float aI0 = 0.f, aI1 = 0.f, la = 0.f;
    const int d0i = rpD[n], d1i = rpD[n + 1];
    for (int i = d0i; i < d1i; ++i) {
        const int e = __builtin_amdgcn_readfirstlane(eidD[i]);
        const float* ea = eattr + (long)e * ED;
        la += ea[lane];
        float d0 = bb0, d1 = bb1;
        #pragma unroll
        for (int k = 0; k < 64; ++k) {
            float a = ea[k];
            d0 = fmaf(a, w0r[k], d0);
            d1 = fmaf(a, w1r[k], d1);
        }
        aI0 += fmaxf(d0, 0.f);
        aI1 += fmaxf(d1, 0.f);
    }

    const float invS = 1.f / (float)((s1 - s0) > 1 ? (s1 - s0) : 1);
    const float invD = 1.f / (float)((d1i - d0i) > 1 ? (d1i - d0i) : 1);
    float* xrow = x_input + (long)n * 256;
    xrow[lane]        = aO0 * invS;
    xrow[64 + lane]   = aO1 * invS;
    xrow[128 + lane]  = aI0 * invD;
    xrow[192 + lane]  = aI1 * invD;
    loopa[(long)n * ED + lane] = la * invD;
}

// =====================================================================
// K3: generic dense GEMM  C[M,NC] = A[M,KD] @ W[KD,NC]
// =====================================================================
template<int KD, int NC>
__global__ __launch_bounds__(256) void k_gemm(const float* __restrict__ A,
                                              const float* __restrict__ W,
                                              float* __restrict__ C, int M)
{
    constexpr int CPW = NC / 4;
    __shared__ float a_lds[64][65];
    const int lane = threadIdx.x & 63;
    const int wid  = __builtin_amdgcn_readfirstlane(threadIdx.x >> 6);
    const int r0   = blockIdx.x * 64;
    const int row  = r0 + lane;

    float acc[CPW];
    #pragma unroll
    for (int j = 0; j < CPW; ++j) acc[j] = 0.f;

    for (int k0 = 0; k0 < KD; k0 += 64) {
        __syncthreads();
        for (int r = wid; r < 64; r += 4) {
            int rr = r0 + r;
            a_lds[r][lane] = (rr < M) ? A[(long)rr * KD + k0 + lane] : 0.f;
        }
        __syncthreads();
        for (int k = 0; k < 64; ++k) {
            float a = a_lds[lane][k];
            const float* wrow = W + (long)(k0 + k) * NC + wid * CPW;
            #pragma unroll
            for (int j = 0; j < CPW; ++j) acc[j] = fmaf(a, wrow[j], acc[j]);
        }
    }
    if (row < M) {
        float* crow = C + (long)row * NC + wid * CPW;
        #pragma unroll
        for (int j = 0; j < CPW; ++j) crow[j] = acc[j];
    }
}

// =====================================================================
// K4: per augmented edge: ee = ea@we; msg = leaky(ee+xl[s]+xr[d]);
//     logits = msg . att  (stored, no atomics)
// =====================================================================
template<int HEADS>
__global__ __launch_bounds__(256) void k_gat_logits(
    const float* __restrict__ eattr, const int* __restrict__ src, const int* __restrict__ dst,
    const float* __restrict__ loopa,
    const float* __restrict__ xl, const float* __restrict__ xr,
    const float* __restrict__ we, const float* __restrict__ att,
    float* __restrict__ logits)
{
    constexpr int OC  = HEADS * 128;
    constexpr int CPW = OC / 4;
    __shared__ float ea_lds[64][65];
    __shared__ float p_lds[4][64];
    const int lane = threadIdx.x & 63;
    const int wid  = __builtin_amdgcn_readfirstlane(threadIdx.x >> 6);
    const long e0  = (long)blockIdx.x * 64;

    for (int r = wid; r < 64; r += 4) {
        long e = e0 + r;
        float v = 0.f;
        if (e < EA) {
            const float* ap = (e < NE) ? (eattr + e * ED) : (loopa + (e - NE) * ED);
            v = ap[lane];
        }
        ea_lds[r][lane] = v;
    }
    __syncthreads();

    const long e  = e0 + lane;
    const bool val = (e < EA);
    int s = 0, d = 0;
    if (val) { if (e < NE) { s = src[e]; d = dst[e]; } else { s = d = (int)(e - NE); } }
    const int c0 = wid * CPW;

    float acc[CPW];
    #pragma unroll
    for (int j = 0; j < CPW; ++j) acc[j] = 0.f;
    for (int k = 0; k < 64; ++k) {
        float a = ea_lds[lane][k];
        const float* wrow = we + (long)k * OC + c0;
        #pragma unroll
        for (int j = 0; j < CPW; ++j) acc[j] = fmaf(a, wrow[j], acc[j]);
    }

    const float* xlr = xl + (long)s * OC + c0;
    const float* xrr = xr + (long)d * OC + c0;
    float part = 0.f;
    #pragma unroll
    for (int j = 0; j < CPW; ++j) {
        float m = acc[j] + xlr[j] + xrr[j];
        m = (m > 0.f) ? m : 0.2f * m;                  // leaky_relu(0.2)
        part = fmaf(m, att[c0 + j], part);
    }
    p_lds[wid][lane] = part;
    __syncthreads();

    if (wid == 0 && val) {
        if (HEADS == 2) {
            logits[e * 2 + 0] = p_lds[0][lane] + p_lds[1][lane];
            logits[e * 2 + 1] = p_lds[2][lane] + p_lds[3][lane];
        } else {
            logits[e] = p_lds[0][lane] + p_lds[1][lane] + p_lds[2][lane] + p_lds[3][lane];
        }
    }
}

// =====================================================================
// K5: fused segment softmax + aggregation + head-mean + LN + ELU.
//     Wave per dst node, gather via dst-CSR (+ implicit self loop).
// =====================================================================
template<int HEADS>
__global__ __launch_bounds__(256) void k_gat_reduce(
    const int* __restrict__ rpD, const int* __restrict__ eidD,
    const int* __restrict__ src,
    const float* __restrict__ xl, const float* __restrict__ logits,
    const float* __restrict__ bias, const float* __restrict__ g, const float* __restrict__ b,
    float* __restrict__ hout)
{
    constexpr int OC = HEADS * 128;
    const int lane = threadIdx.x & 63;
    const int n = blockIdx.x * 4 + (threadIdx.x >> 6);
    if (n >= NN) return;

    const int base = rpD[n];
    const int deg  = rpD[n + 1] - base;
    const int nea  = deg + 1;                          // + self loop

    float m0 = -1e30f, m1 = -1e30f;
    for (int i = lane; i < nea; i += 64) {
        int e = (i < deg) ? eidD[base + i] : (NE + n);
        m0 = fmaxf(m0, logits[(long)e * HEADS + 0]);
        if (HEADS == 2) m1 = fmaxf(m1, logits[(long)e * HEADS + 1]);
    }
    #pragma unroll
    for (int off = 32; off; off >>= 1) {
        m0 = fmaxf(m0, __shfl_xor(m0, off));
        if (HEADS == 2) m1 = fmaxf(m1, __shfl_xor(m1, off));
    }

    float s0 = 0.f, s1 = 0.f;
    for (int i = lane; i < nea; i += 64) {
        int e = (i < deg) ? eidD[base + i] : (NE + n);
        s0 += __expf(logits[(long)e * HEADS + 0] - m0);
        if (HEADS == 2) s1 += __expf(logits[(long)e * HEADS + 1] - m1);
    }
    #pragma unroll
    for (int off = 32; off; off >>= 1) {
        s0 += __shfl_xor(s0, off);
        if (HEADS == 2) s1 += __shfl_xor(s1, off);
    }
    const float inv0 = 1.f / (s0 + 1e-16f);
    const float inv1 = 1.f / (s1 + 1e-16f);

    float a0 = 0.f, a1 = 0.f, a2 = 0.f, a3 = 0.f;
    for (int i = 0; i < nea; ++i) {
        const int e  = __builtin_amdgcn_readfirstlane((i < deg) ? eidD[base + i] : (NE + n));
        const int sN = (e < NE) ? src[e] : (e - NE);
        const float w0 = __expf(logits[(long)e * HEADS + 0] - m0) * inv0;
        const float* xrow = xl + (long)sN * OC;
        a0 = fmaf(xrow[lane],      w0, a0);
        a1 = fmaf(xrow[64 + lane], w0, a1);
        if (HEADS == 2) {
            const float w1 = __expf(logits[(long)e * HEADS + 1] - m1) * inv1;
            a2 = fmaf(xrow[128 + lane], w1, a2);
            a3 = fmaf(xrow[192 + lane], w1, a3);
        }
    }

    float v0, v1;
    if (HEADS == 2) { v0 = 0.5f * (a0 + a2); v1 = 0.5f * (a1 + a3); }
    else            { v0 = a0;               v1 = a1; }
    v0 += bias[lane];
    v1 += bias[64 + lane];

    float sum = v0 + v1;
    #pragma unroll
    for (int off = 32; off; off >>= 1) sum += __shfl_xor(sum, off);
    const float mu = sum * (1.f / 128.f);
    const float q0 = v0 - mu, q1 = v1 - mu;
    float vs = q0 * q0 + q1 * q1;
    #pragma unroll
    for (int off = 32; off; off >>= 1) vs += __shfl_xor(vs, off);
    const float rstd = rsqrtf(vs * (1.f / 128.f) + 1e-5f);

    float y0 = q0 * rstd * g[lane]      + b[lane];
    float y1 = q1 * rstd * g[64 + lane] + b[64 + lane];
    hout[(long)n * 128 + lane]      = (y0 > 0.f) ? y0 : (__expf(y0) - 1.f);
    hout[(long)n * 128 + 64 + lane] = (y1 > 0.f) ? y1 : (__expf(y1) - 1.f);
}

// =====================================================================
// K8: classifier with node-decomposed layer 1.
//   z1 = relu(Ps[src] + Pd[dst] + ea@We1 + b1);  We1 = c1_w rows 256..319
//   z2 = relu(z1 @ c2_w + b2);  out = z2 @ c3_w + b3
// =====================================================================
__global__ __launch_bounds__(256) void k_classifier(
    const float* __restrict__ Ps, const float* __restrict__ Pd,
    const int* __restrict__ src, const int* __restrict__ dst,
    const float* __restrict__ eattr,
    const float* __restrict__ c1we, const float* __restrict__ c1b,
    const float* __restrict__ c2w, const float* __restrict__ c2b,
    const float* __restrict__ c3w, const float* __restrict__ c3b,
    float* __restrict__ out)
{
    __shared__ float smem[128 * 65];     // phase1: ea [64][65]; phase2: z1^T [128][65]
    __shared__ float p_lds[4][64];
    const int lane = threadIdx.x & 63;
    const int wid  = __builtin_amdgcn_readfirstlane(threadIdx.x >> 6);
    const long e0  = (long)blockIdx.x * 64;
    const long e   = e0 + lane;
    const bool val = (e < NE);
    const int c0   = wid * 32;

    // stage ea rows (coalesced)
    for (int rr = wid; rr < 64; rr += 4) {
        long ee = e0 + rr;
        smem[rr * 65 + lane] = (ee < NE) ? eattr[ee * ED + lane] : 0.f;
    }
    __syncthreads();

    // layer 1: ea @ We1 + bias
    float acc[32];
    #pragma unroll
    for (int j = 0; j < 32; ++j) acc[j] = c1b[c0 + j];
    for (int k = 0; k < 64; ++k) {
        float a = smem[lane * 65 + k];
        const float* wrow = c1we + (long)k * 128 + c0;
        #pragma unroll
        for (int j = 0; j < 32; ++j) acc[j] = fmaf(a, wrow[j], acc[j]);
    }

    // + gathered node projections (per-lane contiguous 128B from each)
    const int sN = val ? src[e] : 0;
    const int dN = val ? dst[e] : 0;
    const float* ps = Ps + (long)sN * 128 + c0;
    const float* pd = Pd + (long)dN * 128 + c0;
    #pragma unroll
    for (int j = 0; j < 32; ++j) acc[j] += ps[j] + pd[j];

    __syncthreads();                                     // ea staging dead
    #pragma unroll
    for (int j = 0; j < 32; ++j) smem[(c0 + j) * 65 + lane] = fmaxf(acc[j], 0.f);  // z1^T
    __syncthreads();

    // layer 2: z1 @ c2_w (wid owns 16 cols), then layer-3 dot
    float acc2[16];
    #pragma unroll
    for (int j = 0; j < 16; ++j) acc2[j] = c2b[wid * 16 + j];
    for (int k = 0; k < 128; ++k) {
        float a = smem[k * 65 + lane];
        const float* wrow = c2w + (long)k * 64 + wid * 16;
        #pragma unroll
        for (int j = 0; j < 16; ++j) acc2[j] = fmaf(a, wrow[j], acc2[j]);
    }
    float part = 0.f;
    #pragma unroll
    for (int j = 0; j < 16; ++j) part = fmaf(fmaxf(acc2[j], 0.f), c3w[wid * 16 + j], part);
    p_lds[wid][lane] = part;
    __syncthreads();
    if (wid == 0 && val)
        out[e] = p_lds[0][lane] + p_lds[1][lane] + p_lds[2][lane] + p_lds[3][lane] + c3b[0];
}

// =====================================================================
extern "C" void kernel_launch(void* const* d_in, const int* in_sizes, int n_in,
                              void* d_out, int out_size, void* d_ws, size_t ws_size,
                              hipStream_t stream)
{
    const int*   edge_index = (const int*)  d_in[1];
    const float* edge_attr  = (const float*)d_in[2];
    const float* ep_w  = (const float*)d_in[3];
    const float* ep_b  = (const float*)d_in[4];
    const float* g1_wl = (const float*)d_in[5];
    const float* g1_wr = (const float*)d_in[6];
    const float* g1_we = (const float*)d_in[7];
    const float* g1_att= (const float*)d_in[8];
    const float* g1_b  = (const float*)d_in[9];
    const float* n1_g  = (const float*)d_in[10];
    const float* n1_b  = (const float*)d_in[11];
    const float* g2_wl = (const float*)d_in[12];
    const float* g2_wr = (const float*)d_in[13];
    const float* g2_we = (const float*)d_in[14];
    const float* g2_att= (const float*)d_in[15];
    const float* g2_b  = (const float*)d_in[16];
    const float* n2_g  = (const float*)d_in[17];
    const float* n2_b  = (const float*)d_in[18];
    const float* c1_w  = (const float*)d_in[19];
    const float* c1_b  = (const float*)d_in[20];
    const float* c2_w  = (const float*)d_in[21];
    const float* c2_b  = (const float*)d_in[22];
    const float* c3_w  = (const float*)d_in[23];
    const float* c3_b  = (const float*)d_in[24];
    const int* src = edge_index;
    const int* dst = edge_index + NE;

    // ---- workspace layout ----
    char* wsb = (char*)d_ws;
    size_t o = 0;
    auto alloc = [&](size_t bytes) { void* p = wsb + o; o += (bytes + 255) & ~(size_t)255; return p; };
    int* cntS = (int*)alloc(NN * 4);          // cntS+cntD must stay first (one memset)
    int* cntD = (int*)alloc(NN * 4);
    int* curS = (int*)alloc(NN * 4);
    int* curD = (int*)alloc(NN * 4);
    int* rpS  = (int*)alloc((NN + 1) * 4);
    int* rpD  = (int*)alloc((NN + 1) * 4);
    int* eidS = (int*)alloc((size_t)NE * 4);
    int* eidD = (int*)alloc((size_t)NE * 4);
    float* loopa   = (float*)alloc((size_t)NN * 64 * 4);
    float* x_input = (float*)alloc((size_t)NN * 256 * 4);   // reused: h2
    float* xl1     = (float*)alloc((size_t)NN * 256 * 4);   // reused: xl2, Ps
    float* xr1     = (float*)alloc((size_t)NN * 256 * 4);   // reused: xr2, Pd
    float* logits  = (float*)alloc((size_t)EA * 2 * 4);
    float* h1      = (float*)alloc((size_t)NN * 128 * 4);
    float* xl2 = xl1;
    float* xr2 = xr1;
    float* h2  = x_input;
    float* Ps  = xl1;            // free after k_gat_reduce<1>
    float* Pd  = xr1;

    // ---- CSR build ----
    hipMemsetAsync(d_ws, 0, 2 * ((NN * 4 + 255) & ~255), stream);   // cntS + cntD
    k_hist<<<(NE + 255) / 256, 256, 0, stream>>>(src, dst, cntS, cntD);
    k_scan<<<1, 1024, 0, stream>>>(cntS, cntD, rpS, rpD, curS, curD);
    k_scatter<<<(NE + 255) / 256, 256, 0, stream>>>(src, dst, curS, curD, eidS, eidD);

    // ---- stage 1: node input features (no atomics) ----
    k_node_inputs<<<(NN + 3) / 4, 256, 0, stream>>>(edge_attr, rpS, eidS, rpD, eidD,
                                                    ep_w, ep_b, x_input, loopa);

    // ---- GAT layer 1 (heads=2) ----
    k_gemm<256, 256><<<(NN + 63) / 64, 256, 0, stream>>>(x_input, g1_wl, xl1, NN);
    k_gemm<256, 256><<<(NN + 63) / 64, 256, 0, stream>>>(x_input, g1_wr, xr1, NN);
    k_gat_logits<2><<<(EA + 63) / 64, 256, 0, stream>>>(edge_attr, src, dst, loopa, xl1, xr1, g1_we, g1_att, logits);
    k_gat_reduce<2><<<(NN + 3) / 4, 256, 0, stream>>>(rpD, eidD, src, xl1, logits, g1_b, n1_g, n1_b, h1);

    // ---- GAT layer 2 (heads=1) ----
    k_gemm<128, 128><<<(NN + 63) / 64, 256, 0, stream>>>(h1, g2_wl, xl2, NN);
    k_gemm<128, 128><<<(NN + 63) / 64, 256, 0, stream>>>(h1, g2_wr, xr2, NN);
    k_gat_logits<1><<<(EA + 63) / 64, 256, 0, stream>>>(edge_attr, src, dst, loopa, xl2, xr2, g2_we, g2_att, logits);
    k_gat_reduce<1><<<(NN + 3) / 4, 256, 0, stream>>>(rpD, eidD, src, xl2, logits, g2_b, n2_g, n2_b, h2);

    // ---- classifier: node-decomposed layer 1 ----
    k_gemm<128, 128><<<(NN + 63) / 64, 256, 0, stream>>>(h2, c1_w,             Ps, NN);
    k_gemm<128, 128><<<(NN + 63) / 64, 256, 0, stream>>>(h2, c1_w + 128 * 128, Pd, NN);
    k_classifier<<<(NE + 63) / 64, 256, 0, stream>>>(Ps, Pd, src, dst, edge_attr,
                                                     c1_w + 256 * 128, c1_b, c2_w, c2_b, c3_w, c3_b,
                                                     (float*)d_out);
}